// Round 8
// baseline (581.893 us; speedup 1.0000x reference)
//
#include <hip/hip_runtime.h>
#include <stdint.h>

#define B_   8
#define S_   2048
#define HID_ 512
#define M_   (B_ * S_)   // 16384
#define AW_  5
#define NB_  512u        // mega grid size (2 blocks/CU x 256 CUs)

typedef __attribute__((ext_vector_type(8))) short bf16x8;
typedef __attribute__((ext_vector_type(4))) float f32x4;
typedef unsigned short u16;

__device__ __forceinline__ u16 f2bf(float f) {
    uint32_t u = __builtin_bit_cast(uint32_t, f);
    u += 0x7FFFu + ((u >> 16) & 1u);   // RNE
    return (u16)(u >> 16);
}
__device__ __forceinline__ float bf2f(u16 h) {
    uint32_t u = ((uint32_t)h) << 16;
    return __builtin_bit_cast(float, u);
}

// async global->LDS, 16B/lane (dest = wave-uniform base + lane*16, linear)
__device__ __forceinline__ void gload16(const void* g, void* l) {
    __builtin_amdgcn_global_load_lds(
        (const __attribute__((address_space(1))) void*)(uintptr_t)g,
        (__attribute__((address_space(3))) void*)(uint32_t)(uintptr_t)l,
        16, 0, 0);
}

// ---------------------------------------------------------------------------
// device-wide barrier (all NB_ blocks co-resident by construction):
// release fence -> block sync -> 1 atomic arrive/block -> spin -> acquire.
// (__builtin_amdgcn_fence: this ROCm lacks the __hip_atomic_fence wrapper)
// ---------------------------------------------------------------------------
__device__ __forceinline__ void gridbar(unsigned* c) {
    __builtin_amdgcn_fence(__ATOMIC_RELEASE, "agent");
    __syncthreads();
    if (threadIdx.x == 0) {
        __hip_atomic_fetch_add(c, 1u, __ATOMIC_ACQ_REL, __HIP_MEMORY_SCOPE_AGENT);
        while (__hip_atomic_load(c, __ATOMIC_ACQUIRE, __HIP_MEMORY_SCOPE_AGENT) < NB_)
            __builtin_amdgcn_s_sleep(2);
    }
    __syncthreads();
    __builtin_amdgcn_fence(__ATOMIC_ACQUIRE, "agent");
}

// ---------------------------------------------------------------------------
// P0: one 32x32 transpose job W[k][n] f32 -> Wt[n][k] bf16
// ---------------------------------------------------------------------------
__device__ __forceinline__ void prep_job(float* tile, const float* src,
                                         u16* dst, int n0, int k0) {
    const int tr = threadIdx.x >> 5, tc = threadIdx.x & 31;
    __syncthreads();   // protect tile reuse (prev job / prev LDS use)
#pragma unroll
    for (int p = 0; p < 4; ++p)
        tile[(tr + p * 8) * 33 + tc] = src[(long)(k0 + tr + p * 8) * HID_ + n0 + tc];
    __syncthreads();
#pragma unroll
    for (int p = 0; p < 4; ++p)
        dst[(long)(n0 + tr + p * 8) * HID_ + k0 + tc] = f2bf(tile[tc * 33 + tr + p * 8]);
}

// ---------------------------------------------------------------------------
// P1: h = relu(x @ W1 + b1), A f32 (cvt fused via reg-staging). 128x128,
// BK=64, 2-buf LDS, T2 swizzle, XCD swizzle. (R4-proven body)
// LDS map: A buffers at AB[0,32KB), B buffers at AB+32KB.
// ---------------------------------------------------------------------------
__device__ __forceinline__ void gemm1_phase(char* AB, const float* A,
                                            const u16* Bt, const float* bias,
                                            u16* C, int bid) {
    char* Abase = AB;
    char* Bbase = AB + 32768;

    const int tid = threadIdx.x;
    const int swz = (bid & 7) * 64 + (bid >> 3);   // 512 blocks, bijective
    const int  bn   = (swz & 3) * 128;
    const long brow = (long)(swz >> 2) * 128;

    const int w  = tid >> 6;
    const int l  = tid & 63;
    const int wm = (w >> 1) * 64;
    const int wn = (w & 1) * 64;
    const int lr  = l & 15;
    const int lkb = (l >> 4) * 16;
    const int sw  = (lr & 7) << 4;

    const int r0 = tid >> 2;
    const int c0 = (tid & 3) * 16;
    const int r1 = 64 + r0;
    const float* ga0 = A + (brow + r0) * 512 + c0;
    const float* ga1 = A + (brow + r1) * 512 + c0;
    const int wb00 = r0 * 128 + ((c0 * 2 +  0) ^ ((r0 & 7) << 4));
    const int wb01 = r0 * 128 + ((c0 * 2 + 16) ^ ((r0 & 7) << 4));
    const int wb10 = r1 * 128 + ((c0 * 2 +  0) ^ ((r1 & 7) << 4));
    const int wb11 = r1 * 128 + ((c0 * 2 + 16) ^ ((r1 & 7) << 4));

    int pq[4];
    const u16* srcB[4];
#pragma unroll
    for (int q = 0; q < 4; ++q) {
        const int p   = tid * 16 + q * 4096;
        const int row = p >> 7;
        const int cb  = (p & 127) ^ ((row & 7) << 4);
        pq[q]   = p;
        srcB[q] = Bt + (long)(bn + row) * 512 + (cb >> 1);
    }

    f32x4 acc[4][4];
#pragma unroll
    for (int i = 0; i < 4; ++i)
#pragma unroll
        for (int j = 0; j < 4; ++j) {
            f32x4 z = {0.f, 0.f, 0.f, 0.f};
            acc[i][j] = z;
        }

    float4 ra[4], rb[4];

#define LOADA(k0)                                                        \
    {                                                                    \
        _Pragma("unroll") for (int u = 0; u < 4; ++u) {                  \
            ra[u] = *(const float4*)(ga0 + (k0) + u * 4);                \
            rb[u] = *(const float4*)(ga1 + (k0) + u * 4);                \
        }                                                                \
    }
#define CVTWRITE(buf)                                                    \
    {                                                                    \
        union { u16 u[8]; int4 v; } q0, q1, q2, q3;                      \
        q0.u[0]=f2bf(ra[0].x); q0.u[1]=f2bf(ra[0].y); q0.u[2]=f2bf(ra[0].z); q0.u[3]=f2bf(ra[0].w); \
        q0.u[4]=f2bf(ra[1].x); q0.u[5]=f2bf(ra[1].y); q0.u[6]=f2bf(ra[1].z); q0.u[7]=f2bf(ra[1].w); \
        q1.u[0]=f2bf(ra[2].x); q1.u[1]=f2bf(ra[2].y); q1.u[2]=f2bf(ra[2].z); q1.u[3]=f2bf(ra[2].w); \
        q1.u[4]=f2bf(ra[3].x); q1.u[5]=f2bf(ra[3].y); q1.u[6]=f2bf(ra[3].z); q1.u[7]=f2bf(ra[3].w); \
        q2.u[0]=f2bf(rb[0].x); q2.u[1]=f2bf(rb[0].y); q2.u[2]=f2bf(rb[0].z); q2.u[3]=f2bf(rb[0].w); \
        q2.u[4]=f2bf(rb[1].x); q2.u[5]=f2bf(rb[1].y); q2.u[6]=f2bf(rb[1].z); q2.u[7]=f2bf(rb[1].w); \
        q3.u[0]=f2bf(rb[2].x); q3.u[1]=f2bf(rb[2].y); q3.u[2]=f2bf(rb[2].z); q3.u[3]=f2bf(rb[2].w); \
        q3.u[4]=f2bf(rb[3].x); q3.u[5]=f2bf(rb[3].y); q3.u[6]=f2bf(rb[3].z); q3.u[7]=f2bf(rb[3].w); \
        *(int4*)(Abase + (buf) * 16384 + wb00) = q0.v;                   \
        *(int4*)(Abase + (buf) * 16384 + wb01) = q1.v;                   \
        *(int4*)(Abase + (buf) * 16384 + wb10) = q2.v;                   \
        *(int4*)(Abase + (buf) * 16384 + wb11) = q3.v;                   \
    }
#define STAGEB(buf, k0)                                                  \
    {                                                                    \
        _Pragma("unroll") for (int q = 0; q < 4; ++q)                    \
            gload16(srcB[q] + (k0), Bbase + (buf) * 16384 + pq[q]);      \
    }

    LOADA(0);
    STAGEB(0, 0);
    CVTWRITE(0);
    __syncthreads();

    int cur = 0;
    for (int t = 0; t < 8; ++t) {
        if (t < 7) {
            LOADA((t + 1) * 64);
            STAGEB(cur ^ 1, (t + 1) * 64);
        }
#pragma unroll
        for (int kk = 0; kk < 2; ++kk) {
            bf16x8 af[4], bfr[4];
#pragma unroll
            for (int i = 0; i < 4; ++i) {
                const int off = (wm + i * 16 + lr) * 128 + ((kk * 64 + lkb) ^ sw);
                af[i] = *(const bf16x8*)(Abase + cur * 16384 + off);
            }
#pragma unroll
            for (int j = 0; j < 4; ++j) {
                const int off = (wn + j * 16 + lr) * 128 + ((kk * 64 + lkb) ^ sw);
                bfr[j] = *(const bf16x8*)(Bbase + cur * 16384 + off);
            }
#pragma unroll
            for (int i = 0; i < 4; ++i)
#pragma unroll
                for (int j = 0; j < 4; ++j)
                    acc[i][j] = __builtin_amdgcn_mfma_f32_16x16x32_bf16(
                        af[i], bfr[j], acc[i][j], 0, 0, 0);
        }
        if (t < 7) CVTWRITE(cur ^ 1);
        __syncthreads();
        cur ^= 1;
    }
#undef LOADA
#undef CVTWRITE
#undef STAGEB

    float bv[4];
#pragma unroll
    for (int j = 0; j < 4; ++j) bv[j] = bias[bn + wn + j * 16 + lr];
    const int rq = (l >> 4) * 4;
#pragma unroll
    for (int i = 0; i < 4; ++i)
#pragma unroll
        for (int q = 0; q < 4; ++q) {
            const long row = brow + wm + i * 16 + rq + q;
            u16* crow = C + row * 512 + bn + wn + lr;
#pragma unroll
            for (int j = 0; j < 4; ++j)
                crow[j * 16] = f2bf(fmaxf(acc[i][j][q] + bv[j], 0.f));
        }
}

// ---------------------------------------------------------------------------
// P2/P4: bf16 GEMM 128x128, BK=64, 2-buf, T2+XCD swizzle. (R4-proven body)
// EPI 0: C bf16 write. EPI 1: relu+bias then dot with Wfc -> 8-slot partials.
// ---------------------------------------------------------------------------
template <int EPI>
__device__ __forceinline__ void gemm_phase(char* AB, const u16* A, const u16* Bt,
                                           const float* b2, const float* Wfc,
                                           u16* C, float* partials, int bid) {
    char* Abase = AB;
    char* Bbase = AB + 32768;

    const int tid = threadIdx.x;
    const int swz = (bid & 7) * 64 + (bid >> 3);
    const int  bn   = (swz & 3) * 128;
    const long brow = (long)(swz >> 2) * 128;

    const int w  = tid >> 6;
    const int l  = tid & 63;
    const int wm = (w >> 1) * 64;
    const int wn = (w & 1) * 64;
    const int lr  = l & 15;
    const int lkb = (l >> 4) * 16;
    const int sw  = (lr & 7) << 4;

    int pq[4];
    const u16* srcA[4];
    const u16* srcB[4];
#pragma unroll
    for (int q = 0; q < 4; ++q) {
        const int p   = tid * 16 + q * 4096;
        const int row = p >> 7;
        const int cb  = (p & 127) ^ ((row & 7) << 4);
        pq[q]   = p;
        srcA[q] = A  + (brow + row) * 512 + (cb >> 1);
        srcB[q] = Bt + (long)(bn + row) * 512 + (cb >> 1);
    }

    f32x4 acc[4][4];
#pragma unroll
    for (int i = 0; i < 4; ++i)
#pragma unroll
        for (int j = 0; j < 4; ++j) {
            f32x4 z = {0.f, 0.f, 0.f, 0.f};
            acc[i][j] = z;
        }

#define STAGE(buf, k0)                                                   \
    {                                                                    \
        _Pragma("unroll") for (int q = 0; q < 4; ++q) {                  \
            gload16(srcA[q] + (k0), Abase + (buf) * 16384 + pq[q]);      \
            gload16(srcB[q] + (k0), Bbase + (buf) * 16384 + pq[q]);      \
        }                                                                \
    }

    int cur = 0;
    STAGE(0, 0);
    __syncthreads();

    for (int t = 0; t < 8; ++t) {
        if (t < 7) STAGE(cur ^ 1, (t + 1) * 64);
#pragma unroll
        for (int kk = 0; kk < 2; ++kk) {
            bf16x8 af[4], bfr[4];
#pragma unroll
            for (int i = 0; i < 4; ++i) {
                const int off = (wm + i * 16 + lr) * 128 + ((kk * 64 + lkb) ^ sw);
                af[i] = *(const bf16x8*)(Abase + cur * 16384 + off);
            }
#pragma unroll
            for (int j = 0; j < 4; ++j) {
                const int off = (wn + j * 16 + lr) * 128 + ((kk * 64 + lkb) ^ sw);
                bfr[j] = *(const bf16x8*)(Bbase + cur * 16384 + off);
            }
#pragma unroll
            for (int i = 0; i < 4; ++i)
#pragma unroll
                for (int j = 0; j < 4; ++j)
                    acc[i][j] = __builtin_amdgcn_mfma_f32_16x16x32_bf16(
                        af[i], bfr[j], acc[i][j], 0, 0, 0);
        }
        __syncthreads();
        cur ^= 1;
    }
#undef STAGE

    const int rq = (l >> 4) * 4;
    if (EPI == 0) {
#pragma unroll
        for (int i = 0; i < 4; ++i)
#pragma unroll
            for (int q = 0; q < 4; ++q) {
                const long row = brow + wm + i * 16 + rq + q;
                u16* crow = C + row * 512 + bn + wn + lr;
#pragma unroll
                for (int j = 0; j < 4; ++j)
                    crow[j * 16] = f2bf(acc[i][j][q]);
            }
    } else {
        float bvv[4], w0v[4], w1v[4];
#pragma unroll
        for (int j = 0; j < 4; ++j) {
            const int col = bn + wn + j * 16 + lr;
            bvv[j] = b2[col];
            w0v[j] = Wfc[2 * col];
            w1v[j] = Wfc[2 * col + 1];
        }
        const int slot = (bn >> 7) * 2 + (wn >> 6);   // 0..7
#pragma unroll
        for (int i = 0; i < 4; ++i)
#pragma unroll
            for (int q = 0; q < 4; ++q) {
                float s0 = 0.f, s1 = 0.f;
#pragma unroll
                for (int j = 0; j < 4; ++j) {
                    const float v = fmaxf(acc[i][j][q] + bvv[j], 0.f);
                    s0 += v * w0v[j];
                    s1 += v * w1v[j];
                }
#pragma unroll
                for (int m = 1; m < 16; m <<= 1) {
                    s0 += __shfl_xor(s0, m);
                    s1 += __shfl_xor(s1, m);
                }
                if (lr == 0) {
                    const long row = brow + wm + i * 16 + rq + q;
                    float* pp = partials + ((long)slot * M_ + row) * 2;
                    pp[0] = s0;
                    pp[1] = s1;
                }
            }
    }
}

// ---------------------------------------------------------------------------
// P3: one winsum element-chunk: aw[bs,:] = sum_{d=-5..5} g[bs+d,:]
// ---------------------------------------------------------------------------
__device__ __forceinline__ void winsum_step(const u16* g, u16* awb, float* awf,
                                            long idx) {
    const int  c8 = (int)(idx & 63);
    const long bs = idx >> 6;
    const int  s  = (int)(bs & (S_ - 1));

    float acc[8] = {};
#pragma unroll
    for (int d = -AW_; d <= AW_; ++d) {
        const int ss = s + d;
        if (0 <= ss && ss < S_) {
            const int4 v = *(const int4*)&g[(bs + d) * HID_ + c8 * 8];
            const u16* u = (const u16*)&v;
#pragma unroll
            for (int e = 0; e < 8; ++e) acc[e] += bf2f(u[e]);
        }
    }
    union { u16 u[8]; int4 v; } r;
#pragma unroll
    for (int e = 0; e < 8; ++e) r.u[e] = f2bf(acc[e]);
    *(int4*)&awb[bs * HID_ + c8 * 8] = r.v;
    float4 o0 = {acc[0], acc[1], acc[2], acc[3]};
    float4 o1 = {acc[4], acc[5], acc[6], acc[7]};
    *(float4*)&awf[bs * HID_ + c8 * 8]     = o0;
    *(float4*)&awf[bs * HID_ + c8 * 8 + 4] = o1;
}

// ---------------------------------------------------------------------------
// P5: out[row] = sum_8 partials + bfc (rows bid*256+tid)
// ---------------------------------------------------------------------------
__device__ __forceinline__ void fcred_step(const float* partials, const float* bfc,
                                           float* out, int bid) {
    const int row = bid * 256 + threadIdx.x;
    float s0 = bfc[0], s1 = bfc[1];
#pragma unroll
    for (int p = 0; p < 8; ++p) {
        s0 += partials[((long)p * M_ + row) * 2 + 0];
        s1 += partials[((long)p * M_ + row) * 2 + 1];
    }
    out[row * 2 + 0] = s0;
    out[row * 2 + 1] = s1;
}

// ---------------------------------------------------------------------------
// counter zeroing (re-runs every replay -> deterministic)
// ---------------------------------------------------------------------------
__global__ void zero_cnt(unsigned* c) {
    if (threadIdx.x < 8) c[threadIdx.x] = 0;
}

// ---------------------------------------------------------------------------
// MEGA: all phases, one dispatch, 512 blocks (2/CU guaranteed: 64KB LDS,
// launch_bounds(256,2) caps VGPR<=256 -> 8 waves/CU).
// ---------------------------------------------------------------------------
__global__ __launch_bounds__(256, 2) void mega(
    const float* x, const float* W1, const float* b1,
    const float* Wv, const float* W2, const float* b2,
    const float* Wfc, const float* bfc,
    u16* W1t, u16* Wvt, u16* W2t,
    u16* h, u16* g, float* partials,
    float* aw_f32, float* out, unsigned* cnt) {
    __shared__ __attribute__((aligned(16))) u16 L[4 * 128 * 64];   // 64KB
    const int bid = blockIdx.x;

    // P0: 768 transpose jobs over 512 blocks
    {
        float* tile = (float*)&L[0];
        for (int j = bid; j < 768; j += (int)NB_) {
            const int wsel = j >> 8, t = j & 255;
            const float* src = wsel == 0 ? W1 : (wsel == 1 ? Wv : W2);
            u16* dst = wsel == 0 ? W1t : (wsel == 1 ? Wvt : W2t);
            prep_job(tile, src, dst, (t & 15) * 32, (t >> 4) * 32);
        }
    }
    gridbar(&cnt[0]);
    // P1: h = relu(x @ W1 + b1)
    gemm1_phase((char*)&L[0], x, W1t, b1, h, bid);
    gridbar(&cnt[1]);
    // P2: g = h @ Wv
    gemm_phase<0>((char*)&L[0], h, Wvt, nullptr, nullptr, g, nullptr, bid);
    gridbar(&cnt[2]);
    // P3: aw = winsum11(g) -> awb (h region) + aw_f32 (output 2)
    for (int it = 0; it < 8; ++it)
        winsum_step(g, h, aw_f32, (long)it * (NB_ * 256) + bid * 256 + threadIdx.x);
    gridbar(&cnt[3]);
    // P4: partials = relu(aw @ W2 + b2) @ Wfc
    gemm_phase<1>((char*)&L[0], h, W2t, b2, Wfc, nullptr, partials, bid);
    gridbar(&cnt[4]);
    // P5: out = sum partials + bfc
    if (bid < 64) fcred_step(partials, bfc, out, bid);
}

// ---------------------------------------------------------------------------
// fallback wrappers (ws too small for mega layout) — R4-proven flow
// ---------------------------------------------------------------------------
__global__ __launch_bounds__(256) void k_prep(const float* W1, const float* Wv,
                                              const float* W2, u16* W1t,
                                              u16* Wvt, u16* W2t, int do_w2) {
    __shared__ float tile[32 * 33];
    const int wsel = blockIdx.x >> 8;
    if (wsel == 2 && !do_w2) return;
    const float* src = wsel == 0 ? W1 : (wsel == 1 ? Wv : W2);
    u16* dst = wsel == 0 ? W1t : (wsel == 1 ? Wvt : W2t);
    const int t = blockIdx.x & 255;
    prep_job(tile, src, dst, (t & 15) * 32, (t >> 4) * 32);
}
__global__ __launch_bounds__(256) void k_prep1(const float* W2, u16* W2t) {
    __shared__ float tile[32 * 33];
    const int t = blockIdx.x;
    prep_job(tile, W2, W2t, (t & 15) * 32, (t >> 4) * 32);
}
__global__ __launch_bounds__(256, 2) void k_gemm1(const float* A, const u16* Bt,
                                                  const float* bias, u16* C) {
    __shared__ __attribute__((aligned(16))) u16 L[4 * 128 * 64];
    gemm1_phase((char*)&L[0], A, Bt, bias, C, blockIdx.x);
}
__global__ __launch_bounds__(256, 2) void k_gemm2(const u16* A, const u16* Bt,
                                                  u16* C) {
    __shared__ __attribute__((aligned(16))) u16 L[4 * 128 * 64];
    gemm_phase<0>((char*)&L[0], A, Bt, nullptr, nullptr, C, nullptr, blockIdx.x);
}
__global__ __launch_bounds__(256, 2) void k_gemm4(const u16* A, const u16* Bt,
                                                  const float* b2, const float* Wfc,
                                                  float* partials) {
    __shared__ __attribute__((aligned(16))) u16 L[4 * 128 * 64];
    gemm_phase<1>((char*)&L[0], A, Bt, b2, Wfc, nullptr, partials, blockIdx.x);
}
__global__ __launch_bounds__(256) void k_winsum(const u16* g, u16* awb, float* awf) {
    winsum_step(g, awb, awf, (long)blockIdx.x * 256 + threadIdx.x);
}
__global__ __launch_bounds__(256) void k_fcred(const float* partials,
                                               const float* bfc, float* out) {
    fcred_step(partials, bfc, out, blockIdx.x);
}

// ---------------------------------------------------------------------------
extern "C" void kernel_launch(void* const* d_in, const int* in_sizes, int n_in,
                              void* d_out, int out_size, void* d_ws, size_t ws_size,
                              hipStream_t stream) {
    const float* x   = (const float*)d_in[0];
    const float* W1  = (const float*)d_in[1];
    const float* b1  = (const float*)d_in[2];
    // d_in[3]=Wq, d_in[4]=Wk dead: softmax over singleton axis == 1.0
    const float* Wv  = (const float*)d_in[5];
    const float* W2  = (const float*)d_in[6];
    const float* b2  = (const float*)d_in[7];
    const float* Wfc = (const float*)d_in[8];
    const float* bfc = (const float*)d_in[9];

    float* out_part = (float*)d_out;                 // 16384*2 f32
    float* aw_f32   = (float*)d_out + (long)M_ * 2;  // 16384*512 f32 (32MB) "Q"

    unsigned char* ws = (unsigned char*)d_ws;

    // Q doubles as scratch until P3 overwrites it with the f32 aw output:
    u16* W1t = (u16*)aw_f32;            // 512KB, dead after gemm1
    u16* Wvt = W1t + 262144;            // 512KB, dead after gemm2

    u16* h   = (u16*)ws;                           // [0,16M): h, then awb
    u16* g   = (u16*)ws + 8388608;                 // [16M,32M): g (dead after P3)
    float* partials = (float*)(ws + (17l << 20));  // 1MB in dead-g region

    const bool big = ws_size >= ((size_t)35 << 20);

    if (big) {
        u16* W2t = (u16*)(ws + (33l << 20));           // 512KB
        unsigned* cnt = (unsigned*)(ws + (34l << 20)); // 32B counters
        zero_cnt<<<1, 64, 0, stream>>>(cnt);
        mega<<<NB_, 256, 0, stream>>>(x, W1, b1, Wv, W2, b2, Wfc, bfc,
                                      W1t, Wvt, W2t, h, g, partials,
                                      aw_f32, out_part, cnt);
    } else {
        u16* W2t = g;   // late transpose into dead-g region
        k_prep<<<768, 256, 0, stream>>>(W1, Wv, W2, W1t, Wvt, W2t, 0);
        k_gemm1<<<512, 256, 0, stream>>>(x, W1t, b1, h);
        k_gemm2<<<512, 256, 0, stream>>>(h, Wvt, g);
        k_winsum<<<4096, 256, 0, stream>>>(g, h, aw_f32);
        k_prep1<<<256, 256, 0, stream>>>(W2, W2t);
        k_gemm4<<<512, 256, 0, stream>>>(h, W2t, b2, Wfc, partials);
        k_fcred<<<64, 256, 0, stream>>>(partials, bfc, out_part);
    }
}

// Round 9
// 79.756 us; speedup vs baseline: 7.2959x; 7.2959x over previous
//
#include <hip/hip_runtime.h>
#include <stdint.h>

#define B_   8
#define S_   2048
#define HID_ 512
#define M_   (B_ * S_)   // 16384
#define AW_  5

typedef __attribute__((ext_vector_type(8))) short bf16x8;
typedef __attribute__((ext_vector_type(4))) float f32x4;
typedef unsigned short u16;

__device__ __forceinline__ u16 f2bf(float f) {
    uint32_t u = __builtin_bit_cast(uint32_t, f);
    u += 0x7FFFu + ((u >> 16) & 1u);   // RNE
    return (u16)(u >> 16);
}
__device__ __forceinline__ float bf2f(u16 h) {
    uint32_t u = ((uint32_t)h) << 16;
    return __builtin_bit_cast(float, u);
}

// async global->LDS, 16B/lane (dest = wave-uniform base + lane*16, linear)
__device__ __forceinline__ void gload16(const void* g, void* l) {
    __builtin_amdgcn_global_load_lds(
        (const __attribute__((address_space(1))) void*)(uintptr_t)g,
        (__attribute__((address_space(3))) void*)(uint32_t)(uintptr_t)l,
        16, 0, 0);
}

#define WAITV(n)  asm volatile("s_waitcnt vmcnt(" #n ")" ::: "memory")
#define WAITLG0() asm volatile("s_waitcnt lgkmcnt(0)" ::: "memory")

// ---------------------------------------------------------------------------
// prep: W1^T, Wv^T always; W2^T if do_w2. 768 blocks (256 per weight).
// ---------------------------------------------------------------------------
__global__ __launch_bounds__(256) void prep_w(const float* __restrict__ W1,
                                              const float* __restrict__ Wv,
                                              const float* __restrict__ W2,
                                              u16* __restrict__ W1t,
                                              u16* __restrict__ Wvt,
                                              u16* __restrict__ W2t,
                                              int do_w2) {
    const int wsel = blockIdx.x >> 8;
    if (wsel == 2 && !do_w2) return;
    const float* src = wsel == 0 ? W1 : (wsel == 1 ? Wv : W2);
    u16* dst = wsel == 0 ? W1t : (wsel == 1 ? Wvt : W2t);
    const int t  = blockIdx.x & 255;
    const int n0 = (t & 15) * 32, k0 = (t >> 4) * 32;
    __shared__ float tile[32][33];
    const int tr = threadIdx.x >> 5, tc = threadIdx.x & 31;
#pragma unroll
    for (int p = 0; p < 4; ++p)
        tile[tr + p * 8][tc] = src[(long)(k0 + tr + p * 8) * HID_ + n0 + tc];
    __syncthreads();
#pragma unroll
    for (int p = 0; p < 4; ++p)
        dst[(long)(n0 + tr + p * 8) * HID_ + k0 + tc] = f2bf(tile[tc][tr + p * 8]);
}

__global__ __launch_bounds__(256) void trans_w2(const float* __restrict__ W2,
                                                u16* __restrict__ W2t) {
    __shared__ float tile[32][33];
    const int k0 = blockIdx.y * 32, n0 = blockIdx.x * 32;
    const int tr = threadIdx.x >> 5, tc = threadIdx.x & 31;
#pragma unroll
    for (int p = 0; p < 4; ++p)
        tile[tr + p * 8][tc] = W2[(long)(k0 + tr + p * 8) * HID_ + n0 + tc];
    __syncthreads();
#pragma unroll
    for (int p = 0; p < 4; ++p)
        W2t[(long)(n0 + tr + p * 8) * HID_ + k0 + tc] = f2bf(tile[tc][tr + p * 8]);
}

// ---------------------------------------------------------------------------
// gemm1: h = relu(x @ W1 + b1), A f32 (cvt fused via reg-staging). 128x128,
// BK=64, 2-buf LDS, T2 swizzle, XCD swizzle. (R4-proven body)
// ---------------------------------------------------------------------------
__global__ __launch_bounds__(256, 2) void gemm1_f32a(const float* __restrict__ A,
                                                     const u16* __restrict__ Bt,
                                                     const float* __restrict__ bias,
                                                     u16* __restrict__ C) {
    __shared__ __attribute__((aligned(16))) u16 As[2][128 * 64];
    __shared__ __attribute__((aligned(16))) u16 Bs[2][128 * 64];

    const int tid = threadIdx.x;
    const int bid = blockIdx.x;
    const int swz = (bid & 7) * 64 + (bid >> 3);   // 512 blocks, bijective
    const int  bn   = (swz & 3) * 128;
    const long brow = (long)(swz >> 2) * 128;

    const int w  = tid >> 6;
    const int l  = tid & 63;
    const int wm = (w >> 1) * 64;
    const int wn = (w & 1) * 64;
    const int lr  = l & 15;
    const int lkb = (l >> 4) * 16;
    const int sw  = (lr & 7) << 4;

    const int r0 = tid >> 2;
    const int c0 = (tid & 3) * 16;
    const int r1 = 64 + r0;
    const float* ga0 = A + (brow + r0) * 512 + c0;
    const float* ga1 = A + (brow + r1) * 512 + c0;
    char* lw = (char*)&As[0][0];
    const int wb00 = r0 * 128 + ((c0 * 2 +  0) ^ ((r0 & 7) << 4));
    const int wb01 = r0 * 128 + ((c0 * 2 + 16) ^ ((r0 & 7) << 4));
    const int wb10 = r1 * 128 + ((c0 * 2 +  0) ^ ((r1 & 7) << 4));
    const int wb11 = r1 * 128 + ((c0 * 2 + 16) ^ ((r1 & 7) << 4));

    int pq[4];
    const u16* srcB[4];
#pragma unroll
    for (int q = 0; q < 4; ++q) {
        const int p   = tid * 16 + q * 4096;
        const int row = p >> 7;
        const int cb  = (p & 127) ^ ((row & 7) << 4);
        pq[q]   = p;
        srcB[q] = Bt + (long)(bn + row) * 512 + (cb >> 1);
    }

    f32x4 acc[4][4];
#pragma unroll
    for (int i = 0; i < 4; ++i)
#pragma unroll
        for (int j = 0; j < 4; ++j) {
            f32x4 z = {0.f, 0.f, 0.f, 0.f};
            acc[i][j] = z;
        }

    float4 ra[4], rb[4];

#define LOADA(k0)                                                        \
    {                                                                    \
        _Pragma("unroll") for (int u = 0; u < 4; ++u) {                  \
            ra[u] = *(const float4*)(ga0 + (k0) + u * 4);                \
            rb[u] = *(const float4*)(ga1 + (k0) + u * 4);                \
        }                                                                \
    }
#define CVTWRITE(buf)                                                    \
    {                                                                    \
        union { u16 u[8]; int4 v; } q0, q1, q2, q3;                      \
        q0.u[0]=f2bf(ra[0].x); q0.u[1]=f2bf(ra[0].y); q0.u[2]=f2bf(ra[0].z); q0.u[3]=f2bf(ra[0].w); \
        q0.u[4]=f2bf(ra[1].x); q0.u[5]=f2bf(ra[1].y); q0.u[6]=f2bf(ra[1].z); q0.u[7]=f2bf(ra[1].w); \
        q1.u[0]=f2bf(ra[2].x); q1.u[1]=f2bf(ra[2].y); q1.u[2]=f2bf(ra[2].z); q1.u[3]=f2bf(ra[2].w); \
        q1.u[4]=f2bf(ra[3].x); q1.u[5]=f2bf(ra[3].y); q1.u[6]=f2bf(ra[3].z); q1.u[7]=f2bf(ra[3].w); \
        q2.u[0]=f2bf(rb[0].x); q2.u[1]=f2bf(rb[0].y); q2.u[2]=f2bf(rb[0].z); q2.u[3]=f2bf(rb[0].w); \
        q2.u[4]=f2bf(rb[1].x); q2.u[5]=f2bf(rb[1].y); q2.u[6]=f2bf(rb[1].z); q2.u[7]=f2bf(rb[1].w); \
        q3.u[0]=f2bf(rb[2].x); q3.u[1]=f2bf(rb[2].y); q3.u[2]=f2bf(rb[2].z); q3.u[3]=f2bf(rb[2].w); \
        q3.u[4]=f2bf(rb[3].x); q3.u[5]=f2bf(rb[3].y); q3.u[6]=f2bf(rb[3].z); q3.u[7]=f2bf(rb[3].w); \
        *(int4*)(lw + (buf) * 16384 + wb00) = q0.v;                      \
        *(int4*)(lw + (buf) * 16384 + wb01) = q1.v;                      \
        *(int4*)(lw + (buf) * 16384 + wb10) = q2.v;                      \
        *(int4*)(lw + (buf) * 16384 + wb11) = q3.v;                      \
    }
#define STAGEB(buf, k0)                                                  \
    {                                                                    \
        _Pragma("unroll") for (int q = 0; q < 4; ++q)                    \
            gload16(srcB[q] + (k0), (char*)&Bs[buf][0] + pq[q]);         \
    }

    LOADA(0);
    STAGEB(0, 0);
    CVTWRITE(0);
    __syncthreads();

    int cur = 0;
    for (int t = 0; t < 8; ++t) {
        if (t < 7) {
            LOADA((t + 1) * 64);
            STAGEB(cur ^ 1, (t + 1) * 64);
        }
#pragma unroll
        for (int kk = 0; kk < 2; ++kk) {
            bf16x8 af[4], bfr[4];
#pragma unroll
            for (int i = 0; i < 4; ++i) {
                const int off = (wm + i * 16 + lr) * 128 + ((kk * 64 + lkb) ^ sw);
                af[i] = *(const bf16x8*)((const char*)&As[cur][0] + off);
            }
#pragma unroll
            for (int j = 0; j < 4; ++j) {
                const int off = (wn + j * 16 + lr) * 128 + ((kk * 64 + lkb) ^ sw);
                bfr[j] = *(const bf16x8*)((const char*)&Bs[cur][0] + off);
            }
#pragma unroll
            for (int i = 0; i < 4; ++i)
#pragma unroll
                for (int j = 0; j < 4; ++j)
                    acc[i][j] = __builtin_amdgcn_mfma_f32_16x16x32_bf16(
                        af[i], bfr[j], acc[i][j], 0, 0, 0);
        }
        if (t < 7) CVTWRITE(cur ^ 1);
        __syncthreads();
        cur ^= 1;
    }
#undef LOADA
#undef CVTWRITE
#undef STAGEB

    float bv[4];
#pragma unroll
    for (int j = 0; j < 4; ++j) bv[j] = bias[bn + wn + j * 16 + lr];
    const int rq = (l >> 4) * 4;
#pragma unroll
    for (int i = 0; i < 4; ++i)
#pragma unroll
        for (int q = 0; q < 4; ++q) {
            const long row = brow + wm + i * 16 + rq + q;
            u16* crow = C + row * 512 + bn + wn + lr;
#pragma unroll
            for (int j = 0; j < 4; ++j)
                crow[j * 16] = f2bf(fmaxf(acc[i][j][q] + bv[j], 0.f));
        }
}

// ---------------------------------------------------------------------------
// gemm256: R6-PROVEN counted-vmcnt 3-buffer schedule at BM=256, BN=128, BK=64.
// 512 threads = 8 waves (2M x 4N), per-wave output 128x32 (8x2 frags).
// LDS 144KB (3 x (32KB A + 16KB B)), 1 block/CU, grid 256 = 1/CU exactly.
// Sync structure byte-identical to R6 (6 loads/thread/stage, vmcnt(6),
// lgkmcnt(0)+sched_barrier before each barrier; never vmcnt(0) mid-loop).
// + T5 setprio around MFMA cluster.
// EPI 0: C bf16. EPI 1: relu+bias, dot Wfc -> 16-slot partials.
// ---------------------------------------------------------------------------
template <int EPI>
__global__ __launch_bounds__(512, 2) void gemm256(const u16* __restrict__ A,
                                                  const u16* __restrict__ Bt,
                                                  const float* __restrict__ b2,
                                                  const float* __restrict__ Wfc,
                                                  u16* __restrict__ C,
                                                  float* __restrict__ partials) {
    __shared__ __attribute__((aligned(16))) u16 As[3][256 * 64];   // 32KB x3
    __shared__ __attribute__((aligned(16))) u16 Bs[3][128 * 64];   // 16KB x3

    const int tid = threadIdx.x;
    const int bid = blockIdx.x;
    const int swz = (bid & 7) * 32 + (bid >> 3);   // 256 blocks, bijective
    const int  bn   = (swz & 3) * 128;
    const long brow = (long)(swz >> 2) * 256;

    const int w  = tid >> 6;        // 0..7
    const int l  = tid & 63;
    const int wm = (w >> 2) * 128;  // 0 or 128
    const int wn = (w & 3) * 32;    // 0,32,64,96
    const int lr  = l & 15;
    const int lkb = (l >> 4) * 16;
    const int sw  = (lr & 7) << 4;

    // staging: A = 4 gload16/thread (32KB), B = 2 (16KB) -> 6/stage (R6 count)
    int pa[4], pb[2];
    const u16* srcA[4];
    const u16* srcB[2];
#pragma unroll
    for (int q = 0; q < 4; ++q) {
        const int p   = tid * 16 + q * 8192;
        const int row = p >> 7;
        const int cb  = (p & 127) ^ ((row & 7) << 4);
        pa[q]   = p;
        srcA[q] = A + (brow + row) * 512 + (cb >> 1);
    }
#pragma unroll
    for (int q = 0; q < 2; ++q) {
        const int p   = tid * 16 + q * 8192;
        const int row = p >> 7;
        const int cb  = (p & 127) ^ ((row & 7) << 4);
        pb[q]   = p;
        srcB[q] = Bt + (long)(bn + row) * 512 + (cb >> 1);
    }

    f32x4 acc[8][2];
#pragma unroll
    for (int i = 0; i < 8; ++i)
#pragma unroll
        for (int j = 0; j < 2; ++j) {
            f32x4 z = {0.f, 0.f, 0.f, 0.f};
            acc[i][j] = z;
        }

#define STG(buf, k0)                                                     \
    {                                                                    \
        gload16(srcA[0] + (k0), (char*)&As[buf][0] + pa[0]);             \
        gload16(srcA[1] + (k0), (char*)&As[buf][0] + pa[1]);             \
        gload16(srcA[2] + (k0), (char*)&As[buf][0] + pa[2]);             \
        gload16(srcA[3] + (k0), (char*)&As[buf][0] + pa[3]);             \
        gload16(srcB[0] + (k0), (char*)&Bs[buf][0] + pb[0]);             \
        gload16(srcB[1] + (k0), (char*)&Bs[buf][0] + pb[1]);             \
    }

    STG(0, 0);
    STG(1, 64);
    WAITV(6);                          // my buf0 loads landed
    __builtin_amdgcn_s_barrier();      // everyone's buf0 loads landed

#pragma unroll
    for (int t = 0; t < 8; ++t) {
        if (t < 6) {
            const int nb = (t + 2) % 3;
            if (nb == 0)      STG(0, (t + 2) * 64)
            else if (nb == 1) STG(1, (t + 2) * 64)
            else              STG(2, (t + 2) * 64)
        }

        const int cbuf = t % 3;
        const char* ab = cbuf == 0 ? (const char*)&As[0][0]
                       : cbuf == 1 ? (const char*)&As[1][0] : (const char*)&As[2][0];
        const char* bb = cbuf == 0 ? (const char*)&Bs[0][0]
                       : cbuf == 1 ? (const char*)&Bs[1][0] : (const char*)&Bs[2][0];

        __builtin_amdgcn_s_setprio(1);
#pragma unroll
        for (int kk = 0; kk < 2; ++kk) {
            bf16x8 af[8], bfr[2];
#pragma unroll
            for (int j = 0; j < 2; ++j) {
                const int off = (wn + j * 16 + lr) * 128 + ((kk * 64 + lkb) ^ sw);
                bfr[j] = *(const bf16x8*)(bb + off);
            }
#pragma unroll
            for (int i = 0; i < 8; ++i) {
                const int off = (wm + i * 16 + lr) * 128 + ((kk * 64 + lkb) ^ sw);
                af[i] = *(const bf16x8*)(ab + off);
            }
#pragma unroll
            for (int i = 0; i < 8; ++i)
#pragma unroll
                for (int j = 0; j < 2; ++j)
                    acc[i][j] = __builtin_amdgcn_mfma_f32_16x16x32_bf16(
                        af[i], bfr[j], acc[i][j], 0, 0, 0);
        }
        __builtin_amdgcn_s_setprio(0);

        if (t < 7) {
            WAITLG0();                           // my ds_reads of buf t done
            __builtin_amdgcn_sched_barrier(0);   // anti-sink (rule #18)
            if (t < 6) WAITV(6);                 // my buf-(t+1) DMA landed
            else       WAITV(0);                 // t==6: drain last stage
            __builtin_amdgcn_s_barrier();        // publish to all waves
        }
    }
#undef STG

    const int rq = (l >> 4) * 4;
    if (EPI == 0) {
#pragma unroll
        for (int i = 0; i < 8; ++i)
#pragma unroll
            for (int q = 0; q < 4; ++q) {
                const long row = brow + wm + i * 16 + rq + q;
                u16* crow = C + row * 512 + bn + wn + lr;
#pragma unroll
                for (int j = 0; j < 2; ++j)
                    crow[j * 16] = f2bf(acc[i][j][q]);
            }
    } else {
        float bvv[2], w0v[2], w1v[2];
#pragma unroll
        for (int j = 0; j < 2; ++j) {
            const int col = bn + wn + j * 16 + lr;
            bvv[j] = b2[col];
            w0v[j] = Wfc[2 * col];
            w1v[j] = Wfc[2 * col + 1];
        }
        const int slot = (bn >> 7) * 4 + (w & 3);   // 0..15
#pragma unroll
        for (int i = 0; i < 8; ++i)
#pragma unroll
            for (int q = 0; q < 4; ++q) {
                float s0 = 0.f, s1 = 0.f;
#pragma unroll
                for (int j = 0; j < 2; ++j) {
                    const float v = fmaxf(acc[i][j][q] + bvv[j], 0.f);
                    s0 += v * w0v[j];
                    s1 += v * w1v[j];
                }
#pragma unroll
                for (int m = 1; m < 16; m <<= 1) {
                    s0 += __shfl_xor(s0, m);
                    s1 += __shfl_xor(s1, m);
                }
                if (lr == 0) {
                    const long row = brow + wm + i * 16 + rq + q;
                    float* pp = partials + ((long)slot * M_ + row) * 2;
                    pp[0] = s0;
                    pp[1] = s1;
                }
            }
    }
}

// ---------------------------------------------------------------------------
// aw = winsum11(g): bf16 in -> bf16 (for gemm4) AND f32 (final output 2)
// ---------------------------------------------------------------------------
__global__ __launch_bounds__(256) void winsum_f(const u16* __restrict__ g,
                                                u16* __restrict__ awb,
                                                float* __restrict__ awf) {
    const long idx = (long)blockIdx.x * 256 + threadIdx.x;
    const int  c8  = (int)(idx & 63);
    const long bs  = idx >> 6;
    const int  s   = (int)(bs & (S_ - 1));

    float acc[8] = {};
#pragma unroll
    for (int d = -AW_; d <= AW_; ++d) {
        const int ss = s + d;
        if (0 <= ss && ss < S_) {
            const int4 v = *(const int4*)&g[(bs + d) * HID_ + c8 * 8];
            const u16* u = (const u16*)&v;
#pragma unroll
            for (int e = 0; e < 8; ++e) acc[e] += bf2f(u[e]);
        }
    }
    union { u16 u[8]; int4 v; } r;
#pragma unroll
    for (int e = 0; e < 8; ++e) r.u[e] = f2bf(acc[e]);
    *(int4*)&awb[bs * HID_ + c8 * 8] = r.v;
    float4 o0 = {acc[0], acc[1], acc[2], acc[3]};
    float4 o1 = {acc[4], acc[5], acc[6], acc[7]};
    *(float4*)&awf[bs * HID_ + c8 * 8]     = o0;
    *(float4*)&awf[bs * HID_ + c8 * 8 + 4] = o1;
}

// ---------------------------------------------------------------------------
// out[row] = sum_16 partials + bfc
// ---------------------------------------------------------------------------
__global__ __launch_bounds__(256) void fc_reduce(const float* __restrict__ partials,
                                                 const float* __restrict__ bfc,
                                                 float* __restrict__ out) {
    const int row = blockIdx.x * 256 + threadIdx.x;
    float s0 = bfc[0], s1 = bfc[1];
#pragma unroll
    for (int p = 0; p < 16; ++p) {
        s0 += partials[((long)p * M_ + row) * 2 + 0];
        s1 += partials[((long)p * M_ + row) * 2 + 1];
    }
    out[row * 2 + 0] = s0;
    out[row * 2 + 1] = s1;
}

// ---------------------------------------------------------------------------
extern "C" void kernel_launch(void* const* d_in, const int* in_sizes, int n_in,
                              void* d_out, int out_size, void* d_ws, size_t ws_size,
                              hipStream_t stream) {
    const float* x   = (const float*)d_in[0];
    const float* W1  = (const float*)d_in[1];
    const float* b1  = (const float*)d_in[2];
    // d_in[3]=Wq, d_in[4]=Wk dead: softmax over singleton axis == 1.0
    const float* Wv  = (const float*)d_in[5];
    const float* W2  = (const float*)d_in[6];
    const float* b2  = (const float*)d_in[7];
    const float* Wfc = (const float*)d_in[8];
    const float* bfc = (const float*)d_in[9];

    float* out_part = (float*)d_out;                 // 16384*2 f32
    float* aw_f32   = (float*)d_out + (long)M_ * 2;  // 16384*512 f32 (32MB) "Q"

    unsigned char* ws = (unsigned char*)d_ws;

    // Q doubles as scratch until winsum_f overwrites it with the f32 aw:
    u16* W1t = (u16*)aw_f32;            // 512KB, dead after gemm1
    u16* Wvt = W1t + 262144;            // 512KB, dead after gemm2

    // ws layout (proven >= 32MB; fills indicate ~256MB):
    u16* h   = (u16*)ws;                           // [0,16M):  h, then awb
    u16* g   = (u16*)ws + 8388608;                 // [16M,32M): g (dead after winsum)
    u16* awb = h;
    float* partials = (float*)(ws + (17l << 20));  // 2MB @ [17M,19M) (in dead g)

    const bool big = ws_size >= ((size_t)34 << 20);
    u16* W2t = big ? (u16*)(ws + (33l << 20)) : g; // fallback: g-region, late

    // 1) weight prep (+W2 if big ws)
    prep_w<<<768, 256, 0, stream>>>(W1, Wv, W2, W1t, Wvt, W2t, big ? 1 : 0);
    // 2) h = relu(x @ W1 + b1)   (f32->bf16 cvt fused)
    gemm1_f32a<<<512, 256, 0, stream>>>(x, W1t, b1, h);
    // 3) g = h @ Wv              (winsum commutes with Wv)
    gemm256<0><<<256, 512, 0, stream>>>(h, Wvt, nullptr, nullptr, g, nullptr);
    // 4) aw = winsum11(g) -> bf16 (ws) + f32 (output 2, fills Q)
    winsum_f<<<4096, 256, 0, stream>>>(g, awb, aw_f32);
    // 5) fallback: W2^T late, into dead g region
    if (!big)
        trans_w2<<<dim3(16, 16), 256, 0, stream>>>(W2, W2t);
    // 6) partial out = relu(aw @ W2 + b2) @ Wfc   (t never materialized)
    gemm256<1><<<256, 512, 0, stream>>>(awb, W2t, b2, Wfc, nullptr, partials);
    // 7) out = sum partials + bfc
    fc_reduce<<<64, 256, 0, stream>>>(partials, bfc, out_part);
}

// Round 11
// 75.191 us; speedup vs baseline: 7.7388x; 1.0607x over previous
//
#include <hip/hip_runtime.h>
#include <stdint.h>

#define B_   8
#define S_   2048
#define HID_ 512
#define M_   (B_ * S_)   // 16384
#define AW_  5

typedef __attribute__((ext_vector_type(8))) short bf16x8;
typedef __attribute__((ext_vector_type(4))) float f32x4;
typedef unsigned short u16;

__device__ __forceinline__ u16 f2bf(float f) {
    uint32_t u = __builtin_bit_cast(uint32_t, f);
    u += 0x7FFFu + ((u >> 16) & 1u);   // RNE
    return (u16)(u >> 16);
}
__device__ __forceinline__ float bf2f(u16 h) {
    uint32_t u = ((uint32_t)h) << 16;
    return __builtin_bit_cast(float, u);
}

// async global->LDS, 16B/lane (dest = wave-uniform base + lane*16, linear)
__device__ __forceinline__ void gload16(const void* g, void* l) {
    __builtin_amdgcn_global_load_lds(
        (const __attribute__((address_space(1))) void*)(uintptr_t)g,
        (__attribute__((address_space(3))) void*)(uint32_t)(uintptr_t)l,
        16, 0, 0);
}

#define WAITV(n)  asm volatile("s_waitcnt vmcnt(" #n ")" ::: "memory")
#define WAITLG0() asm volatile("s_waitcnt lgkmcnt(0)" ::: "memory")

// ---------------------------------------------------------------------------
// prep: W1^T, Wv^T always; W2^T if do_w2. 768 blocks (256 per weight).
// ---------------------------------------------------------------------------
__global__ __launch_bounds__(256) void prep_w(const float* __restrict__ W1,
                                              const float* __restrict__ Wv,
                                              const float* __restrict__ W2,
                                              u16* __restrict__ W1t,
                                              u16* __restrict__ Wvt,
                                              u16* __restrict__ W2t,
                                              int do_w2) {
    const int wsel = blockIdx.x >> 8;
    if (wsel == 2 && !do_w2) return;
    const float* src = wsel == 0 ? W1 : (wsel == 1 ? Wv : W2);
    u16* dst = wsel == 0 ? W1t : (wsel == 1 ? Wvt : W2t);
    const int t  = blockIdx.x & 255;
    const int n0 = (t & 15) * 32, k0 = (t >> 4) * 32;
    __shared__ float tile[32][33];
    const int tr = threadIdx.x >> 5, tc = threadIdx.x & 31;
#pragma unroll
    for (int p = 0; p < 4; ++p)
        tile[tr + p * 8][tc] = src[(long)(k0 + tr + p * 8) * HID_ + n0 + tc];
    __syncthreads();
#pragma unroll
    for (int p = 0; p < 4; ++p)
        dst[(long)(n0 + tr + p * 8) * HID_ + k0 + tc] = f2bf(tile[tc][tr + p * 8]);
}

__global__ __launch_bounds__(256) void trans_w2(const float* __restrict__ W2,
                                                u16* __restrict__ W2t) {
    __shared__ float tile[32][33];
    const int k0 = blockIdx.y * 32, n0 = blockIdx.x * 32;
    const int tr = threadIdx.x >> 5, tc = threadIdx.x & 31;
#pragma unroll
    for (int p = 0; p < 4; ++p)
        tile[tr + p * 8][tc] = W2[(long)(k0 + tr + p * 8) * HID_ + n0 + tc];
    __syncthreads();
#pragma unroll
    for (int p = 0; p < 4; ++p)
        W2t[(long)(n0 + tr + p * 8) * HID_ + k0 + tc] = f2bf(tile[tc][tr + p * 8]);
}

// ---------------------------------------------------------------------------
// gemm1: h = relu(x @ W1 + b1), A f32 (cvt fused via reg-staging). 128x128,
// BK=64, 2-buf LDS, T2 swizzle, XCD swizzle. (R4-proven body)
// ---------------------------------------------------------------------------
__global__ __launch_bounds__(256, 2) void gemm1_f32a(const float* __restrict__ A,
                                                     const u16* __restrict__ Bt,
                                                     const float* __restrict__ bias,
                                                     u16* __restrict__ C) {
    __shared__ __attribute__((aligned(16))) u16 As[2][128 * 64];
    __shared__ __attribute__((aligned(16))) u16 Bs[2][128 * 64];

    const int tid = threadIdx.x;
    const int bid = blockIdx.x;
    const int swz = (bid & 7) * 64 + (bid >> 3);   // 512 blocks, bijective
    const int  bn   = (swz & 3) * 128;
    const long brow = (long)(swz >> 2) * 128;

    const int w  = tid >> 6;
    const int l  = tid & 63;
    const int wm = (w >> 1) * 64;
    const int wn = (w & 1) * 64;
    const int lr  = l & 15;
    const int lkb = (l >> 4) * 16;
    const int sw  = (lr & 7) << 4;

    const int r0 = tid >> 2;
    const int c0 = (tid & 3) * 16;
    const int r1 = 64 + r0;
    const float* ga0 = A + (brow + r0) * 512 + c0;
    const float* ga1 = A + (brow + r1) * 512 + c0;
    char* lw = (char*)&As[0][0];
    const int wb00 = r0 * 128 + ((c0 * 2 +  0) ^ ((r0 & 7) << 4));
    const int wb01 = r0 * 128 + ((c0 * 2 + 16) ^ ((r0 & 7) << 4));
    const int wb10 = r1 * 128 + ((c0 * 2 +  0) ^ ((r1 & 7) << 4));
    const int wb11 = r1 * 128 + ((c0 * 2 + 16) ^ ((r1 & 7) << 4));

    int pq[4];
    const u16* srcB[4];
#pragma unroll
    for (int q = 0; q < 4; ++q) {
        const int p   = tid * 16 + q * 4096;
        const int row = p >> 7;
        const int cb  = (p & 127) ^ ((row & 7) << 4);
        pq[q]   = p;
        srcB[q] = Bt + (long)(bn + row) * 512 + (cb >> 1);
    }

    f32x4 acc[4][4];
#pragma unroll
    for (int i = 0; i < 4; ++i)
#pragma unroll
        for (int j = 0; j < 4; ++j) {
            f32x4 z = {0.f, 0.f, 0.f, 0.f};
            acc[i][j] = z;
        }

    float4 ra[4], rb[4];

#define LOADA(k0)                                                        \
    {                                                                    \
        _Pragma("unroll") for (int u = 0; u < 4; ++u) {                  \
            ra[u] = *(const float4*)(ga0 + (k0) + u * 4);                \
            rb[u] = *(const float4*)(ga1 + (k0) + u * 4);                \
        }                                                                \
    }
#define CVTWRITE(buf)                                                    \
    {                                                                    \
        union { u16 u[8]; int4 v; } q0, q1, q2, q3;                      \
        q0.u[0]=f2bf(ra[0].x); q0.u[1]=f2bf(ra[0].y); q0.u[2]=f2bf(ra[0].z); q0.u[3]=f2bf(ra[0].w); \
        q0.u[4]=f2bf(ra[1].x); q0.u[5]=f2bf(ra[1].y); q0.u[6]=f2bf(ra[1].z); q0.u[7]=f2bf(ra[1].w); \
        q1.u[0]=f2bf(ra[2].x); q1.u[1]=f2bf(ra[2].y); q1.u[2]=f2bf(ra[2].z); q1.u[3]=f2bf(ra[2].w); \
        q1.u[4]=f2bf(ra[3].x); q1.u[5]=f2bf(ra[3].y); q1.u[6]=f2bf(ra[3].z); q1.u[7]=f2bf(ra[3].w); \
        q2.u[0]=f2bf(rb[0].x); q2.u[1]=f2bf(rb[0].y); q2.u[2]=f2bf(rb[0].z); q2.u[3]=f2bf(rb[0].w); \
        q2.u[4]=f2bf(rb[1].x); q2.u[5]=f2bf(rb[1].y); q2.u[6]=f2bf(rb[1].z); q2.u[7]=f2bf(rb[1].w); \
        q3.u[0]=f2bf(rb[2].x); q3.u[1]=f2bf(rb[2].y); q3.u[2]=f2bf(rb[2].z); q3.u[3]=f2bf(rb[2].w); \
        q3.u[4]=f2bf(rb[3].x); q3.u[5]=f2bf(rb[3].y); q3.u[6]=f2bf(rb[3].z); q3.u[7]=f2bf(rb[3].w); \
        *(int4*)(lw + (buf) * 16384 + wb00) = q0.v;                      \
        *(int4*)(lw + (buf) * 16384 + wb01) = q1.v;                      \
        *(int4*)(lw + (buf) * 16384 + wb10) = q2.v;                      \
        *(int4*)(lw + (buf) * 16384 + wb11) = q3.v;                      \
    }
#define STAGEB(buf, k0)                                                  \
    {                                                                    \
        _Pragma("unroll") for (int q = 0; q < 4; ++q)                    \
            gload16(srcB[q] + (k0), (char*)&Bs[buf][0] + pq[q]);         \
    }

    LOADA(0);
    STAGEB(0, 0);
    CVTWRITE(0);
    __syncthreads();

    int cur = 0;
    for (int t = 0; t < 8; ++t) {
        if (t < 7) {
            LOADA((t + 1) * 64);
            STAGEB(cur ^ 1, (t + 1) * 64);
        }
#pragma unroll
        for (int kk = 0; kk < 2; ++kk) {
            bf16x8 af[4], bfr[4];
#pragma unroll
            for (int i = 0; i < 4; ++i) {
                const int off = (wm + i * 16 + lr) * 128 + ((kk * 64 + lkb) ^ sw);
                af[i] = *(const bf16x8*)((const char*)&As[cur][0] + off);
            }
#pragma unroll
            for (int j = 0; j < 4; ++j) {
                const int off = (wn + j * 16 + lr) * 128 + ((kk * 64 + lkb) ^ sw);
                bfr[j] = *(const bf16x8*)((const char*)&Bs[cur][0] + off);
            }
#pragma unroll
            for (int i = 0; i < 4; ++i)
#pragma unroll
                for (int j = 0; j < 4; ++j)
                    acc[i][j] = __builtin_amdgcn_mfma_f32_16x16x32_bf16(
                        af[i], bfr[j], acc[i][j], 0, 0, 0);
        }
        if (t < 7) CVTWRITE(cur ^ 1);
        __syncthreads();
        cur ^= 1;
    }
#undef LOADA
#undef CVTWRITE
#undef STAGEB

    float bv[4];
#pragma unroll
    for (int j = 0; j < 4; ++j) bv[j] = bias[bn + wn + j * 16 + lr];
    const int rq = (l >> 4) * 4;
#pragma unroll
    for (int i = 0; i < 4; ++i)
#pragma unroll
        for (int q = 0; q < 4; ++q) {
            const long row = brow + wm + i * 16 + rq + q;
            u16* crow = C + row * 512 + bn + wn + lr;
#pragma unroll
            for (int j = 0; j < 4; ++j)
                crow[j * 16] = f2bf(fmaxf(acc[i][j][q] + bv[j], 0.f));
        }
}

// ---------------------------------------------------------------------------
// gemm128: R4-proven 128x128 bf16 GEMM, BK=64, 2-buf, T2+XCD swizzle.
// EPI 0: C bf16 write. EPI 1: relu+bias then dot with Wfc -> 8-slot partials.
// ---------------------------------------------------------------------------
template <int EPI>
__global__ __launch_bounds__(256, 2) void gemm128(const u16* __restrict__ A,
                                                  const u16* __restrict__ Bt,
                                                  const float* __restrict__ b2,
                                                  const float* __restrict__ Wfc,
                                                  u16* __restrict__ C,
                                                  float* __restrict__ partials) {
    __shared__ __attribute__((aligned(16))) u16 As[2][128 * 64];
    __shared__ __attribute__((aligned(16))) u16 Bs[2][128 * 64];

    const int tid = threadIdx.x;
    const int bid = blockIdx.x;
    const int swz = (bid & 7) * 64 + (bid >> 3);
    const int  bn   = (swz & 3) * 128;
    const long brow = (long)(swz >> 2) * 128;

    const int w  = tid >> 6;
    const int l  = tid & 63;
    const int wm = (w >> 1) * 64;
    const int wn = (w & 1) * 64;
    const int lr  = l & 15;
    const int lkb = (l >> 4) * 16;
    const int sw  = (lr & 7) << 4;

    int pq[4];
    const u16* srcA[4];
    const u16* srcB[4];
#pragma unroll
    for (int q = 0; q < 4; ++q) {
        const int p   = tid * 16 + q * 4096;
        const int row = p >> 7;
        const int cb  = (p & 127) ^ ((row & 7) << 4);
        pq[q]   = p;
        srcA[q] = A  + (brow + row) * 512 + (cb >> 1);
        srcB[q] = Bt + (long)(bn + row) * 512 + (cb >> 1);
    }

    f32x4 acc[4][4];
#pragma unroll
    for (int i = 0; i < 4; ++i)
#pragma unroll
        for (int j = 0; j < 4; ++j) {
            f32x4 z = {0.f, 0.f, 0.f, 0.f};
            acc[i][j] = z;
        }

#define STAGE(buf, k0)                                                   \
    {                                                                    \
        _Pragma("unroll") for (int q = 0; q < 4; ++q) {                  \
            gload16(srcA[q] + (k0), (char*)&As[buf][0] + pq[q]);         \
            gload16(srcB[q] + (k0), (char*)&Bs[buf][0] + pq[q]);         \
        }                                                                \
    }

    int cur = 0;
    STAGE(0, 0);
    __syncthreads();

    for (int t = 0; t < 8; ++t) {
        if (t < 7) STAGE(cur ^ 1, (t + 1) * 64);
#pragma unroll
        for (int kk = 0; kk < 2; ++kk) {
            bf16x8 af[4], bfr[4];
#pragma unroll
            for (int i = 0; i < 4; ++i) {
                const int off = (wm + i * 16 + lr) * 128 + ((kk * 64 + lkb) ^ sw);
                af[i] = *(const bf16x8*)((const char*)&As[cur][0] + off);
            }
#pragma unroll
            for (int j = 0; j < 4; ++j) {
                const int off = (wn + j * 16 + lr) * 128 + ((kk * 64 + lkb) ^ sw);
                bfr[j] = *(const bf16x8*)((const char*)&Bs[cur][0] + off);
            }
#pragma unroll
            for (int i = 0; i < 4; ++i)
#pragma unroll
                for (int j = 0; j < 4; ++j)
                    acc[i][j] = __builtin_amdgcn_mfma_f32_16x16x32_bf16(
                        af[i], bfr[j], acc[i][j], 0, 0, 0);
        }
        __syncthreads();
        cur ^= 1;
    }
#undef STAGE

    const int rq = (l >> 4) * 4;
    if (EPI == 0) {
#pragma unroll
        for (int i = 0; i < 4; ++i)
#pragma unroll
            for (int q = 0; q < 4; ++q) {
                const long row = brow + wm + i * 16 + rq + q;
                u16* crow = C + row * 512 + bn + wn + lr;
#pragma unroll
                for (int j = 0; j < 4; ++j)
                    crow[j * 16] = f2bf(acc[i][j][q]);
            }
    } else {
        float bvv[4], w0v[4], w1v[4];
#pragma unroll
        for (int j = 0; j < 4; ++j) {
            const int col = bn + wn + j * 16 + lr;
            bvv[j] = b2[col];
            w0v[j] = Wfc[2 * col];
            w1v[j] = Wfc[2 * col + 1];
        }
        const int slot = (bn >> 7) * 2 + (wn >> 6);   // 0..7
#pragma unroll
        for (int i = 0; i < 4; ++i)
#pragma unroll
            for (int q = 0; q < 4; ++q) {
                float s0 = 0.f, s1 = 0.f;
#pragma unroll
                for (int j = 0; j < 4; ++j) {
                    const float v = fmaxf(acc[i][j][q] + bvv[j], 0.f);
                    s0 += v * w0v[j];
                    s1 += v * w1v[j];
                }
#pragma unroll
                for (int m = 1; m < 16; m <<= 1) {
                    s0 += __shfl_xor(s0, m);
                    s1 += __shfl_xor(s1, m);
                }
                if (lr == 0) {
                    const long row = brow + wm + i * 16 + rq + q;
                    float* pp = partials + ((long)slot * M_ + row) * 2;
                    pp[0] = s0;
                    pp[1] = s1;
                }
            }
    }
}

// ---------------------------------------------------------------------------
// gemm2_ws: g = h @ Wvt computed over 288 rows (256 output + 16/16 halo),
// then winsum fused in the epilogue via LDS: aw = winsum11(g) written as
// bf16 (awb) + f32 (awf).  g never touches HBM.
// K-loop = R6/R9-proven counted-vmcnt 3-buffer schedule; waves 0-3 stage one
// extra halo line (7 loads vs 6; WAITV split is wave-uniform).
// LDS: As[3][288*64] + Bs[3][128*64] = 156 KB; g_lds reuses As[0..1] region.
// ---------------------------------------------------------------------------
__global__ __launch_bounds__(512, 2) void gemm2_ws(const u16* __restrict__ A,
                                                   const u16* __restrict__ Bt,
                                                   u16* __restrict__ awb,
                                                   float* __restrict__ awf) {
    __shared__ __attribute__((aligned(16))) u16 As[3][288 * 64];   // 36864B x3
    __shared__ __attribute__((aligned(16))) u16 Bs[3][128 * 64];   // 16384B x3

    const int tid = threadIdx.x;
    const int bid = blockIdx.x;
    const int swz = (bid & 7) * 32 + (bid >> 3);   // 256 blocks, bijective
    const int  bn   = (swz & 3) * 128;
    const long brow = (long)(swz >> 2) * 256;

    const int w  = tid >> 6;        // 0..7
    const int l  = tid & 63;
    const int wm = (w >> 2) * 144;  // 0 or 144 (both %8==0 -> sw valid)
    const int wn = (w & 3) * 32;
    const int lr  = l & 15;
    const int lkb = (l >> 4) * 16;
    const int sw  = (lr & 7) << 4;
    const bool loww = (tid < 256);  // waves 0..3 stage the halo line

    // A staging: rows brow-16 .. brow+271 (clamped at grid edges; clamped
    // rows are provably excluded by the s-test below).
    int pa[5];
    const u16* srcA[5];
#pragma unroll
    for (int q = 0; q < 4; ++q) {
        const int p   = tid * 16 + q * 8192;
        const int row = p >> 7;
        const int cb  = (p & 127) ^ ((row & 7) << 4);
        long R = brow - 16 + row;
        R = R < 0 ? 0 : (R > M_ - 1 ? M_ - 1 : R);
        pa[q]   = p;
        srcA[q] = A + R * 512 + (cb >> 1);
    }
    pa[4] = 0; srcA[4] = A;
    if (loww) {
        const int p   = 32768 + tid * 16;
        const int row = p >> 7;                       // 256..287
        const int cb  = (p & 127) ^ ((row & 7) << 4);
        long R = brow - 16 + row;
        R = R < 0 ? 0 : (R > M_ - 1 ? M_ - 1 : R);
        pa[4]   = p;
        srcA[4] = A + R * 512 + (cb >> 1);
    }
    int pb[2];
    const u16* srcB[2];
#pragma unroll
    for (int q = 0; q < 2; ++q) {
        const int p   = tid * 16 + q * 8192;
        const int row = p >> 7;
        const int cb  = (p & 127) ^ ((row & 7) << 4);
        pb[q]   = p;
        srcB[q] = Bt + (long)(bn + row) * 512 + (cb >> 1);
    }

    f32x4 acc[9][2];
#pragma unroll
    for (int i = 0; i < 9; ++i)
#pragma unroll
        for (int j = 0; j < 2; ++j) {
            f32x4 z = {0.f, 0.f, 0.f, 0.f};
            acc[i][j] = z;
        }

#define STG(buf, k0)                                                     \
    {                                                                    \
        gload16(srcA[0] + (k0), (char*)&As[buf][0] + pa[0]);             \
        gload16(srcA[1] + (k0), (char*)&As[buf][0] + pa[1]);             \
        gload16(srcA[2] + (k0), (char*)&As[buf][0] + pa[2]);             \
        gload16(srcA[3] + (k0), (char*)&As[buf][0] + pa[3]);             \
        if (loww) gload16(srcA[4] + (k0), (char*)&As[buf][0] + pa[4]);   \
        gload16(srcB[0] + (k0), (char*)&Bs[buf][0] + pb[0]);             \
        gload16(srcB[1] + (k0), (char*)&Bs[buf][0] + pb[1]);             \
    }
#define WAITP()                                                          \
    do {                                                                 \
        if (loww) { WAITV(7); } else { WAITV(6); }                       \
    } while (0)

    STG(0, 0);
    STG(1, 64);
    WAITP();                           // my buf0 loads landed
    __builtin_amdgcn_s_barrier();      // everyone's buf0 loads landed

#pragma unroll
    for (int t = 0; t < 8; ++t) {
        if (t < 6) {
            const int nb = (t + 2) % 3;
            if (nb == 0)      STG(0, (t + 2) * 64)
            else if (nb == 1) STG(1, (t + 2) * 64)
            else              STG(2, (t + 2) * 64)
        }

        const int cbuf = t % 3;
        const char* ab = cbuf == 0 ? (const char*)&As[0][0]
                       : cbuf == 1 ? (const char*)&As[1][0] : (const char*)&As[2][0];
        const char* bb = cbuf == 0 ? (const char*)&Bs[0][0]
                       : cbuf == 1 ? (const char*)&Bs[1][0] : (const char*)&Bs[2][0];

        __builtin_amdgcn_s_setprio(1);
#pragma unroll
        for (int kk = 0; kk < 2; ++kk) {
            bf16x8 af[9], bfr[2];
#pragma unroll
            for (int j = 0; j < 2; ++j) {
                const int off = (wn + j * 16 + lr) * 128 + ((kk * 64 + lkb) ^ sw);
                bfr[j] = *(const bf16x8*)(bb + off);
            }
#pragma unroll
            for (int i = 0; i < 9; ++i) {
                const int off = (wm + i * 16 + lr) * 128 + ((kk * 64 + lkb) ^ sw);
                af[i] = *(const bf16x8*)(ab + off);
            }
#pragma unroll
            for (int i = 0; i < 9; ++i)
#pragma unroll
                for (int j = 0; j < 2; ++j)
                    acc[i][j] = __builtin_amdgcn_mfma_f32_16x16x32_bf16(
                        af[i], bfr[j], acc[i][j], 0, 0, 0);
        }
        __builtin_amdgcn_s_setprio(0);

        if (t < 7) {
            WAITLG0();                           // my ds_reads of buf t done
            __builtin_amdgcn_sched_barrier(0);   // anti-sink (rule #18)
            if (t < 6) { WAITP(); } else { WAITV(0); }   // never 0 mid-loop
            __builtin_amdgcn_s_barrier();        // publish to all waves
        }
    }
#undef STG
#undef WAITP

    // ---- fused winsum epilogue ----
    __syncthreads();                    // all ds_reads done; staging LDS dead
    u16* gl = &As[0][0];                // g_lds [288][128] bf16 = 73728 B

    const int rq4 = (l >> 4) * 4;
#pragma unroll
    for (int i = 0; i < 9; ++i)
#pragma unroll
        for (int j = 0; j < 2; ++j)
#pragma unroll
            for (int q = 0; q < 4; ++q) {
                const int row = wm + i * 16 + rq4 + q;       // 0..287
                const int col = wn + j * 16 + lr;            // 0..127
                gl[row * 128 + col] = f2bf(acc[i][j][q]);
            }
    __syncthreads();

    // wave w: output rows w*32 .. w*32+31; lane l: cols 2l, 2l+1
    for (int rr = 0; rr < 32; ++rr) {
        const int  rloc = w * 32 + rr;
        const long R    = brow + rloc;
        const int  s    = (int)(R & (S_ - 1));
        float a0 = 0.f, a1 = 0.f;
#pragma unroll
        for (int d = -AW_; d <= AW_; ++d) {
            if ((unsigned)(s + d) < (unsigned)S_) {
                const uint32_t v =
                    *(const uint32_t*)&gl[(rloc + 16 + d) * 128 + 2 * l];
                a0 += bf2f((u16)(v & 0xffffu));
                a1 += bf2f((u16)(v >> 16));
            }
        }
        const uint32_t pk = (uint32_t)f2bf(a0) | ((uint32_t)f2bf(a1) << 16);
        *(uint32_t*)&awb[R * 512 + bn + 2 * l] = pk;
        float2 o; o.x = a0; o.y = a1;
        *(float2*)&awf[R * 512 + bn + 2 * l] = o;
    }
}

// ---------------------------------------------------------------------------
// fallback winsum kernel (small-ws path only)
// ---------------------------------------------------------------------------
__global__ __launch_bounds__(256) void winsum_f(const u16* __restrict__ g,
                                                u16* __restrict__ awb,
                                                float* __restrict__ awf) {
    const long idx = (long)blockIdx.x * 256 + threadIdx.x;
    const int  c8  = (int)(idx & 63);
    const long bs  = idx >> 6;
    const int  s   = (int)(bs & (S_ - 1));

    float acc[8] = {};
#pragma unroll
    for (int d = -AW_; d <= AW_; ++d) {
        const int ss = s + d;
        if (0 <= ss && ss < S_) {
            const int4 v = *(const int4*)&g[(bs + d) * HID_ + c8 * 8];
            const u16* u = (const u16*)&v;
#pragma unroll
            for (int e = 0; e < 8; ++e) acc[e] += bf2f(u[e]);
        }
    }
    union { u16 u[8]; int4 v; } r;
#pragma unroll
    for (int e = 0; e < 8; ++e) r.u[e] = f2bf(acc[e]);
    *(int4*)&awb[bs * HID_ + c8 * 8] = r.v;
    float4 o0 = {acc[0], acc[1], acc[2], acc[3]};
    float4 o1 = {acc[4], acc[5], acc[6], acc[7]};
    *(float4*)&awf[bs * HID_ + c8 * 8]     = o0;
    *(float4*)&awf[bs * HID_ + c8 * 8 + 4] = o1;
}

// ---------------------------------------------------------------------------
// out[row] = sum_8 partials + bfc
// ---------------------------------------------------------------------------
__global__ __launch_bounds__(256) void fc_reduce(const float* __restrict__ partials,
                                                 const float* __restrict__ bfc,
                                                 float* __restrict__ out) {
    const int row = blockIdx.x * 256 + threadIdx.x;
    float s0 = bfc[0], s1 = bfc[1];
#pragma unroll
    for (int p = 0; p < 8; ++p) {
        s0 += partials[((long)p * M_ + row) * 2 + 0];
        s1 += partials[((long)p * M_ + row) * 2 + 1];
    }
    out[row * 2 + 0] = s0;
    out[row * 2 + 1] = s1;
}

// ---------------------------------------------------------------------------
extern "C" void kernel_launch(void* const* d_in, const int* in_sizes, int n_in,
                              void* d_out, int out_size, void* d_ws, size_t ws_size,
                              hipStream_t stream) {
    const float* x   = (const float*)d_in[0];
    const float* W1  = (const float*)d_in[1];
    const float* b1  = (const float*)d_in[2];
    // d_in[3]=Wq, d_in[4]=Wk dead: softmax over singleton axis == 1.0
    const float* Wv  = (const float*)d_in[5];
    const float* W2  = (const float*)d_in[6];
    const float* b2  = (const float*)d_in[7];
    const float* Wfc = (const float*)d_in[8];
    const float* bfc = (const float*)d_in[9];

    float* out_part = (float*)d_out;                 // 16384*2 f32
    float* aw_f32   = (float*)d_out + (long)M_ * 2;  // 16384*512 f32 (32MB) "Q"

    unsigned char* ws = (unsigned char*)d_ws;

    const bool big = ws_size >= ((size_t)35 << 20);

    if (big) {
        // ws: h[0,16M) | awb[16M,32M) | W1t/Wvt/W2t[32M..33.5M) | partials
        u16* h    = (u16*)ws;
        u16* awb  = (u16*)(ws + (16l << 20));
        u16* W1t  = (u16*)(ws + (32l << 20));
        u16* Wvt  = W1t + 262144;
        u16* W2t  = Wvt + 262144;
        float* partials = (float*)(ws + (33l << 20) + (1l << 19));

        prep_w<<<768, 256, 0, stream>>>(W1, Wv, W2, W1t, Wvt, W2t, 1);
        gemm1_f32a<<<512, 256, 0, stream>>>(x, W1t, b1, h);
        gemm2_ws<<<256, 512, 0, stream>>>(h, Wvt, awb, aw_f32);
        gemm128<1><<<512, 256, 0, stream>>>(awb, W2t, b2, Wfc, nullptr, partials);
        fc_reduce<<<64, 256, 0, stream>>>(partials, bfc, out_part);
    } else {
        // R4-proven fallback flow (Q scratch + separate winsum)
        u16* W1t = (u16*)aw_f32;            // 512KB, dead after gemm1
        u16* Wvt = W1t + 262144;            // 512KB, dead after gemm2
        u16* h   = (u16*)ws;                           // h, then awb
        u16* g   = (u16*)ws + 8388608;                 // dead after winsum
        u16* awb = h;
        u16* W2t = g;                                  // late transpose target
        float* partials = (float*)(ws + (17l << 20));  // in dead-g region

        prep_w<<<768, 256, 0, stream>>>(W1, Wv, W2, W1t, Wvt, W2t, 0);
        gemm1_f32a<<<512, 256, 0, stream>>>(x, W1t, b1, h);
        gemm128<0><<<512, 256, 0, stream>>>(h, Wvt, nullptr, nullptr, g, nullptr);
        winsum_f<<<4096, 256, 0, stream>>>(g, awb, aw_f32);
        trans_w2<<<dim3(16, 16), 256, 0, stream>>>(W2, W2t);
        gemm128<1><<<512, 256, 0, stream>>>(awb, W2t, b2, Wfc, nullptr, partials);
        fc_reduce<<<64, 256, 0, stream>>>(partials, bfc, out_part);
    }
}